// Round 1
// baseline (317.331 us; speedup 1.0000x reference)
//
#include <hip/hip_runtime.h>
#include <math.h>

// GptOssTopKRouter: X[16384,2880] fp32 @ W[32,2880]^T + b -> top4 -> softmax -> scatter
// Memory-bound on reading X (189 MB). One block per 64 tokens, 8 waves/block,
// each wave owns a 1/8 slice of the hidden dim, all 32 experts in registers.

#define HIDDEN 2880
#define NE 32
#define TOPK 4
#define TPB 64                       // tokens per block (= lanes per wave)
#define NWAVES 8
#define HSPLIT (HIDDEN / NWAVES)     // 360
#define HC 36                        // hidden floats per chunk
#define NCHUNK (HSPLIT / HC)         // 10 (even -> clean 2-deep pipeline)
#define F4 (HC / 4)                  // 9 float4 per lane per chunk

__global__ __launch_bounds__(512, 2)
void router_kernel(const float* __restrict__ x,
                   const float* __restrict__ w,
                   const float* __restrict__ bias,
                   float* __restrict__ out_scores,
                   float* __restrict__ out_idx)
{
    const int lane = threadIdx.x & 63;
    // force wave-uniform SGPR so weight addressing becomes s_load
    const int ws   = __builtin_amdgcn_readfirstlane((int)(threadIdx.x >> 6));
    const int tok  = blockIdx.x * TPB + lane;

    const float* xrow  = x + (size_t)tok * HIDDEN + ws * HSPLIT;
    const float* wbase = w + ws * HSPLIT;     // uniform across the wave

    float acc[NE];
#pragma unroll
    for (int e = 0; e < NE; ++e) acc[e] = 0.0f;

    float4 xa[F4], xb[F4];

#define LOADC(buf, c) do {                                                        \
    _Pragma("unroll")                                                             \
    for (int i = 0; i < F4; ++i)                                                  \
        buf[i] = *reinterpret_cast<const float4*>(xrow + (c) * HC + i * 4);       \
} while (0)

#define COMPUTE(buf, c) do {                                                      \
    _Pragma("unroll")                                                             \
    for (int h4 = 0; h4 < F4; ++h4) {                                             \
        const float x0 = buf[h4].x, x1 = buf[h4].y;                               \
        const float x2 = buf[h4].z, x3 = buf[h4].w;                               \
        _Pragma("unroll")                                                         \
        for (int e = 0; e < NE; ++e) {                                            \
            const float4 w4 = *reinterpret_cast<const float4*>(                   \
                wbase + e * HIDDEN + (c) * HC + h4 * 4);                          \
            acc[e] = fmaf(w4.w, x3,                                               \
                     fmaf(w4.z, x2,                                               \
                     fmaf(w4.y, x1,                                               \
                     fmaf(w4.x, x0, acc[e]))));                                   \
        }                                                                         \
    }                                                                             \
} while (0)

    // 2-deep register double buffer: loads for chunk c+1 in flight during compute c
    LOADC(xa, 0);
    for (int cc = 0; cc < NCHUNK / 2; ++cc) {
        const int c0 = cc * 2;
        LOADC(xb, c0 + 1);
        COMPUTE(xa, c0);
        if (c0 + 2 < NCHUNK) LOADC(xa, c0 + 2);
        COMPUTE(xb, c0 + 1);
    }

#undef LOADC
#undef COMPUTE

    // ---- cross-wave reduction of the 8 h-partials (padded LDS, conflict-free) ----
    __shared__ float part[4][TPB][NE + 1];     // 33.8 KB
    __shared__ float logits[TPB][NE + 1];      //  8.4 KB

    if (ws >= 4) {
#pragma unroll
        for (int e = 0; e < NE; ++e) part[ws - 4][lane][e] = acc[e];
    }
    __syncthreads();
    if (ws < 4) {
#pragma unroll
        for (int e = 0; e < NE; ++e) part[ws][lane][e] += acc[e];
    }
    __syncthreads();

    const int tid = threadIdx.x;
    for (int i2 = tid; i2 < TPB * NE; i2 += 512) {
        const int t2 = i2 >> 5, e2 = i2 & 31;
        float s = bias[e2];
#pragma unroll
        for (int p = 0; p < 4; ++p) s += part[p][t2][e2];
        logits[t2][e2] = s;
    }
    __syncthreads();

    // ---- top-4 + softmax + scatter, one lane per token (wave 0) ----
    if (tid < TPB) {
        float vals[TOPK];
        int   idxs[TOPK];
        unsigned chosen = 0u;
#pragma unroll
        for (int k = 0; k < TOPK; ++k) {
            float m = -INFINITY; int mi = 0;
            for (int e = 0; e < NE; ++e) {
                const float v = logits[tid][e];
                const bool take = (((chosen >> e) & 1u) == 0u) && (v > m);
                m  = take ? v : m;
                mi = take ? e : mi;
            }
            vals[k] = m; idxs[k] = mi; chosen |= (1u << (unsigned)mi);
        }
        const float mx = vals[0];               // descending order: vals[0] is max
        float p[TOPK]; float sum = 0.0f;
#pragma unroll
        for (int k = 0; k < TOPK; ++k) { p[k] = expf(vals[k] - mx); sum += p[k]; }
        const float inv = 1.0f / sum;

        const int t = blockIdx.x * TPB + tid;
        float* srow = out_scores + (size_t)t * NE;
#pragma unroll
        for (int e = 0; e < NE; ++e) {
            float v = 0.0f;
#pragma unroll
            for (int k = 0; k < TOPK; ++k) v = (e == idxs[k]) ? p[k] * inv : v;
            srow[e] = v;
        }
#pragma unroll
        for (int k = 0; k < TOPK; ++k)
            out_idx[(size_t)t * TOPK + k] = (float)idxs[k];   // indices as fp32 values
    }
}

extern "C" void kernel_launch(void* const* d_in, const int* in_sizes, int n_in,
                              void* d_out, int out_size, void* d_ws, size_t ws_size,
                              hipStream_t stream)
{
    const float* x = (const float*)d_in[0];
    const float* w = (const float*)d_in[1];
    const float* b = (const float*)d_in[2];
    const int T = in_sizes[0] / HIDDEN;            // 16384 tokens
    float* out        = (float*)d_out;
    float* out_scores = out;                       // [T, 32]
    float* out_idx    = out + (size_t)T * NE;      // [T, 4] stored as fp32 values

    router_kernel<<<dim3(T / TPB), dim3(512), 0, stream>>>(x, w, b, out_scores, out_idx);
}

// Round 2
// 178.334 us; speedup vs baseline: 1.7794x; 1.7794x over previous
//
#include <hip/hip_runtime.h>
#include <math.h>

// GptOssTopKRouter on MI355X.
// X[16384,2880] fp32 @ W[32,2880]^T + b -> top4 -> softmax -> scatter.
// HBM-bound on X (189 MB). Structure:
//   - pre-kernel transposes W to WT[2880][32] so weights are wave-uniform,
//     consecutive-float rows -> scalar s_load path (zero vector-mem cost).
//   - main kernel: 1 block = 64 tokens = lane index; 8 waves split hidden dim.
//     X streamed in 96-float chunks: coalesced global->reg->LDS (XOR-swizzled),
//     double-buffered, raw s_barrier + manual lgkmcnt (no vmcnt(0) drain).

#define HIDDEN 2880
#define NE 32
#define TOPK 4
#define TPB 64          // tokens per block (= lanes)
#define KC 96           // hidden floats per chunk per token
#define NCH 30          // 2880 / 96
#define SLOTS 24        // float4 slots per row-chunk (96/4)
#define SPW 3           // staging float4s per wave per chunk (24*64/64/8)
#define MPW 12          // hidden floats per wave per chunk (96/8)

__global__ void transpose_w_kernel(const float* __restrict__ w, float* __restrict__ wt) {
    int i = blockIdx.x * 256 + threadIdx.x;
    if (i < NE * HIDDEN) {
        int e = i / HIDDEN;
        int h = i - e * HIDDEN;
        wt[h * NE + e] = w[i];
    }
}

__global__ __launch_bounds__(512, 2)
void router_kernel(const float* __restrict__ x,
                   const float* __restrict__ wt,
                   const float* __restrict__ bias,
                   float* __restrict__ out_scores,
                   float* __restrict__ out_idx)
{
    __shared__ float sm[2 * TPB * KC];          // 2 x 24 KB, reused by epilogue
    float* buf0 = sm;
    float* buf1 = sm + TPB * KC;

    const int tid  = threadIdx.x;
    const int lane = tid & 63;
    const int ws   = __builtin_amdgcn_readfirstlane(tid >> 6);
    const int tok0 = blockIdx.x * TPB;
    const float* __restrict__ xblk = x + (size_t)tok0 * HIDDEN;

    float acc[NE];
#pragma unroll
    for (int e = 0; e < NE; ++e) acc[e] = 0.0f;

    // staging geometry: flat float4 index F4 = (ws*SPW+q)*64 + lane over the
    // 64x24 float4 tile; row = token, slot = float4-in-row (linear on global side)
    int rowq[SPW], sltq[SPW];
    const float* xq[SPW];
#pragma unroll
    for (int q = 0; q < SPW; ++q) {
        int F4 = (ws * SPW + q) * 64 + lane;    // 0..1535
        rowq[q] = F4 / SLOTS;
        sltq[q] = F4 - rowq[q] * SLOTS;
        xq[q]   = xblk + (size_t)rowq[q] * HIDDEN + sltq[q] * 4;
    }

    float4 ga[SPW], gb[SPW];

#define GLOAD(g, c) do { _Pragma("unroll")                                        \
    for (int q = 0; q < SPW; ++q)                                                 \
        g[q] = *reinterpret_cast<const float4*>(xq[q] + (c) * KC);                \
} while (0)

    // XOR-swizzle the destination slot (low 3 bits ^ row) -> conflict-free
    // column-slice ds_read later. Involution: reader applies the same XOR.
#define SWRITE(dst, g) do { _Pragma("unroll")                                     \
    for (int q = 0; q < SPW; ++q) {                                               \
        int jj = (sltq[q] & ~7) | ((sltq[q] ^ rowq[q]) & 7);                      \
        *reinterpret_cast<float4*>((dst) + rowq[q] * KC + jj * 4) = g[q];         \
    }                                                                             \
} while (0)

#define COMPUTE(src, c) do {                                                      \
    float xf[MPW];                                                                \
    _Pragma("unroll")                                                             \
    for (int i = 0; i < SPW; ++i) {                                               \
        int k = ws * SPW + i;                                                     \
        int jj = (k & ~7) | ((k ^ lane) & 7);                                     \
        float4 v = *reinterpret_cast<const float4*>((src) + lane * KC + jj * 4);  \
        xf[i*4+0] = v.x; xf[i*4+1] = v.y; xf[i*4+2] = v.z; xf[i*4+3] = v.w;       \
    }                                                                             \
    const float* __restrict__ wrow = wt + ((size_t)(c) * KC + ws * MPW) * NE;     \
    _Pragma("unroll")                                                             \
    for (int m = 0; m < MPW; ++m) {                                               \
        _Pragma("unroll")                                                         \
        for (int e = 0; e < NE; ++e)                                              \
            acc[e] = fmaf(wrow[m * NE + e], xf[m], acc[e]);                       \
    }                                                                             \
} while (0)

    // raw barrier: do NOT use __syncthreads() in the main loop (it drains
    // vmcnt(0) and kills the global prefetch). ds_writes drained manually.
#define LGKM0_BARRIER() do {                                                      \
    asm volatile("s_waitcnt lgkmcnt(0)" ::: "memory");                            \
    __builtin_amdgcn_s_barrier();                                                 \
} while (0)

    GLOAD(ga, 0);
#pragma unroll 1
    for (int cc = 0; cc < NCH / 2; ++cc) {
        const int c0 = 2 * cc;
        GLOAD(gb, c0 + 1);
        SWRITE(buf0, ga);
        LGKM0_BARRIER();
        COMPUTE(buf0, c0);
        if (c0 + 2 < NCH) GLOAD(ga, c0 + 2);
        SWRITE(buf1, gb);
        LGKM0_BARRIER();
        COMPUTE(buf1, c0 + 1);
    }

#undef GLOAD
#undef SWRITE
#undef COMPUTE
#undef LGKM0_BARRIER

    // ---- epilogue: cross-wave reduction (reuses sm; all vmcnt drained) ----
    float* part   = sm;                  // [4][TPB][NE+1] = 8448 floats
    float* logits = sm + 4 * TPB * (NE + 1);  // [TPB][NE+1] = 2112 floats (total 10560 <= 12288)

    __syncthreads();
    if (ws >= 4) {
#pragma unroll
        for (int e = 0; e < NE; ++e) part[((ws - 4) * TPB + lane) * (NE + 1) + e] = acc[e];
    }
    __syncthreads();
    if (ws < 4) {
#pragma unroll
        for (int e = 0; e < NE; ++e) part[(ws * TPB + lane) * (NE + 1) + e] += acc[e];
    }
    __syncthreads();

    for (int i2 = tid; i2 < TPB * NE; i2 += 512) {
        const int t2 = i2 >> 5, e2 = i2 & 31;
        float s = bias[e2];
#pragma unroll
        for (int p = 0; p < 4; ++p) s += part[(p * TPB + t2) * (NE + 1) + e2];
        logits[t2 * (NE + 1) + e2] = s;
    }
    __syncthreads();

    // ---- top-4 + softmax + scatter, one lane per token (wave 0) ----
    if (tid < TPB) {
        float vals[TOPK];
        int   idxs[TOPK];
        unsigned chosen = 0u;
#pragma unroll
        for (int k = 0; k < TOPK; ++k) {
            float m = -INFINITY; int mi = 0;
            for (int e = 0; e < NE; ++e) {
                const float v = logits[tid * (NE + 1) + e];
                const bool take = (((chosen >> e) & 1u) == 0u) && (v > m);
                m  = take ? v : m;
                mi = take ? e : mi;
            }
            vals[k] = m; idxs[k] = mi; chosen |= (1u << (unsigned)mi);
        }
        const float mx = vals[0];
        float p[TOPK]; float sum = 0.0f;
#pragma unroll
        for (int k = 0; k < TOPK; ++k) { p[k] = expf(vals[k] - mx); sum += p[k]; }
        const float inv = 1.0f / sum;

        const int t = tok0 + tid;
        float* srow = out_scores + (size_t)t * NE;
#pragma unroll
        for (int e = 0; e < NE; ++e) {
            float v = 0.0f;
#pragma unroll
            for (int k = 0; k < TOPK; ++k) v = (e == idxs[k]) ? p[k] * inv : v;
            srow[e] = v;
        }
#pragma unroll
        for (int k = 0; k < TOPK; ++k)
            out_idx[(size_t)t * TOPK + k] = (float)idxs[k];
    }
}

extern "C" void kernel_launch(void* const* d_in, const int* in_sizes, int n_in,
                              void* d_out, int out_size, void* d_ws, size_t ws_size,
                              hipStream_t stream)
{
    const float* x = (const float*)d_in[0];
    const float* w = (const float*)d_in[1];
    const float* b = (const float*)d_in[2];
    const int T = in_sizes[0] / HIDDEN;            // 16384 tokens

    float* wt = (float*)d_ws;                      // [2880][32] = 368.6 KB scratch
    float* out        = (float*)d_out;
    float* out_scores = out;                       // [T, 32]
    float* out_idx    = out + (size_t)T * NE;      // [T, 4] as fp32 values

    transpose_w_kernel<<<dim3((NE * HIDDEN + 255) / 256), dim3(256), 0, stream>>>(w, wt);
    router_kernel<<<dim3(T / TPB), dim3(512), 0, stream>>>(x, wt, b, out_scores, out_idx);
}